// Round 15
// baseline (53.462 us; speedup 1.0000x reference)
//
#include <hip/hip_runtime.h>
#include <math.h>

typedef _Float16 half8 __attribute__((ext_vector_type(8)));
typedef _Float16 h2 __attribute__((ext_vector_type(2)));
typedef float    f32x4 __attribute__((ext_vector_type(4)));
typedef unsigned int u32;
typedef unsigned short u16;

#define BIGV 1e30f
#define ROWB 456             // ring row stride bytes (114 words, gcd(114,32)=2)
#define PAIRB (64 * ROWB)    // 29184 B per pair

__device__ __forceinline__ u32 dpp_shr1(u32 oldv, u32 src) {
  return (u32)__builtin_amdgcn_update_dpp((int)oldv, (int)src, 0x138, 0xF, 0xF, false);
}
__device__ __forceinline__ u16 f2h(float f) {
  union { _Float16 h; u16 u; } c; c.h = (_Float16)f; return c.u;
}
__device__ __forceinline__ u32 pkrtz(float a, float b) {
  auto v = __builtin_amdgcn_cvt_pkrtz(a, b);
  union { decltype(v) h; u32 u; } c; c.h = v; return c.u;
}
__device__ __forceinline__ h2 as_h2(u32 u) { union { u32 u; h2 h; } x; x.u = u; return x.h; }

// Fused self-paced wave: each wave produces (MFMA dist tiles, f32 ring) AND
// consumes (serial DP) its own (b,p) pair. Wave-private ring -> LDS ops are
// hardware-ordered within the wave -> ZERO barriers after staging. 7-slot ring
// window; write slot (k+3)%7 disjoint from read slots {k-3..k+1}%7.
__global__ __launch_bounds__(256) void dtw_fused(
    const float* __restrict__ x,      // (16,16,1024)
    const float* __restrict__ patts,  // (64,16,64)
    float* __restrict__ out,          // (16,64,64,64)
    float wd) {
  __shared__ uint4 xsq[2050];          // f16-packed x columns + zero block @2048
  __shared__ u16   x2h16[1024];        // ||x_t||^2 as f16
  __shared__ float ringf[4 * 64 * 114]; // 4 pairs x 64 rows x 456B

  const int tid = threadIdx.x, lane = tid & 63, wv = tid >> 6;
  const int b = blockIdx.x >> 4, pg = blockIdx.x & 15;
  const int p = pg * 4 + wv;
  const int le = lane & 15, kq = lane >> 4;

  // ---- stage x (block-wide, only sync in the kernel) ----
  {
    const float* xb = x + b * (16 * 1024);
    u16* xh = (u16*)xsq;
    for (int idx = tid; idx < 16384; idx += 256) {
      int d = idx >> 10, t = idx & 1023;
      xh[t * 16 + d] = f2h(xb[idx]);
    }
    if (tid == 0) { xsq[2048] = make_uint4(0,0,0,0); xsq[2049] = make_uint4(0,0,0,0); }
    __syncthreads();
    for (int t = tid; t < 1024; t += 256) {
      uint4 a0 = xsq[2 * t], a1 = xsq[2 * t + 1];
      float s2 = __builtin_amdgcn_fdot2(as_h2(a0.x), as_h2(a0.x), 0.f, false);
      s2 = __builtin_amdgcn_fdot2(as_h2(a0.y), as_h2(a0.y), s2, false);
      s2 = __builtin_amdgcn_fdot2(as_h2(a0.z), as_h2(a0.z), s2, false);
      s2 = __builtin_amdgcn_fdot2(as_h2(a0.w), as_h2(a0.w), s2, false);
      s2 = __builtin_amdgcn_fdot2(as_h2(a1.x), as_h2(a1.x), s2, false);
      s2 = __builtin_amdgcn_fdot2(as_h2(a1.y), as_h2(a1.y), s2, false);
      s2 = __builtin_amdgcn_fdot2(as_h2(a1.z), as_h2(a1.z), s2, false);
      s2 = __builtin_amdgcn_fdot2(as_h2(a1.w), as_h2(a1.w), s2, false);
      x2h16[t] = f2h(s2);
    }
  }
  __syncthreads();   // staging complete; no further block sync

  // ---- B fragments: -2p in k<16; k16=1, k17=p2 (validated norm-fold) ----
  half8 bf[4];
  {
    const float* pp = patts + p * (16 * 64);
#pragma unroll
    for (int nb = 0; nb < 4; ++nb) {
      float pv[8]; float part = 0.f;
#pragma unroll
      for (int j = 0; j < 8; ++j) {
        float f = (kq < 2) ? pp[(8 * kq + j) * 64 + nb * 16 + le] : 0.f;
        pv[j] = f; part = fmaf(f, f, part);
      }
      part += __shfl_xor(part, 16, 64);
      part += __shfl_xor(part, 32, 64);
      u32 wd0 = pkrtz(-2.f * pv[0], -2.f * pv[1]);
      u32 wd1 = pkrtz(-2.f * pv[2], -2.f * pv[3]);
      u32 wd2 = pkrtz(-2.f * pv[4], -2.f * pv[5]);
      u32 wd3 = pkrtz(-2.f * pv[6], -2.f * pv[7]);
      if (kq == 2) { wd0 = 0x3C00u | ((u32)f2h(part) << 16); wd1 = 0; wd2 = 0; wd3 = 0; }
      union { uint4 q; half8 h; } bu; bu.q = make_uint4(wd0, wd1, wd2, wd3);
      bf[nb] = bu.h;
    }
  }

  // ---- producer state ----
  char* wrow = (char*)ringf + wv * PAIRB + le * ROWB;   // row for nb=0; +16*ROWB per nb
  u32 colp = 0;                                          // byte col of current produce slot

#define PRODUCE(T0) { \
    int aidx_ = (kq < 2) ? (2 * ((T0) + le) + kq) : 2048; \
    uint4 aq_ = xsq[aidx_]; \
    u32 x2b_ = (u32)x2h16[(T0) + le]; \
    aq_.x = (kq == 2) ? (x2b_ | 0x3C000000u) : aq_.x; \
    union { uint4 q; half8 h; } au_; au_.q = aq_; \
    u32 wo_ = colp + (u32)(16 * kq); \
    _Pragma("unroll") \
    for (int nb_ = 0; nb_ < 4; ++nb_) { \
      f32x4 c_ = {0.f, 0.f, 0.f, 0.f}; \
      c_ = __builtin_amdgcn_mfma_f32_16x16x32_f16(au_.h, bf[nb_], c_, 0, 0, 0); \
      float d0_ = __builtin_amdgcn_sqrtf(fmaxf(c_[0], 1e-12f)); \
      float d1_ = __builtin_amdgcn_sqrtf(fmaxf(c_[1], 1e-12f)); \
      float d2_ = __builtin_amdgcn_sqrtf(fmaxf(c_[2], 1e-12f)); \
      float d3_ = __builtin_amdgcn_sqrtf(fmaxf(c_[3], 1e-12f)); \
      char* wb_ = wrow + nb_ * (16 * ROWB) + wo_; \
      *(float2*)(wb_)     = make_float2(d0_, d1_); \
      *(float2*)(wb_ + 8) = make_float2(d2_, d3_); \
    } \
    colp += 64u; if (colp >= 448u) colp -= 448u; }

  // ---- consumer state (stagger-1, validated chain) ----
  const char* crow = (const char*)ringf + wv * PAIRB + lane * ROWB;
  u32 colb = 448u - 8u * (u32)((lane + 1) >> 1);
  if (colb == 448u) colb = 0u;
  const bool oddl = (lane & 1) != 0;
  const int bigbits = __float_as_int(BIGV);
  float prev = BIGV, shA = BIGV, shB = BIGV, pend = 0.f;
  float* oprow = out + ((b * 64 + p) * 64 + lane) * 64;

#define W448(X) ((X) >= 448u ? (X) - 448u : (X))
#define LOAD9(Q0,Q1,Q2,Q3,Q4,Q5,Q6,Q7,Q8) { \
    Q0 = *(const float2*)(crow + colb); \
    Q1 = *(const float2*)(crow + W448(colb + 8u)); \
    Q2 = *(const float2*)(crow + W448(colb + 16u)); \
    Q3 = *(const float2*)(crow + W448(colb + 24u)); \
    Q4 = *(const float2*)(crow + W448(colb + 32u)); \
    Q5 = *(const float2*)(crow + W448(colb + 40u)); \
    Q6 = *(const float2*)(crow + W448(colb + 48u)); \
    Q7 = *(const float2*)(crow + W448(colb + 56u)); \
    Q8 = *(const float2*)(crow + W448(colb + 64u)); \
    colb = W448(colb + 64u); }

#define DPS(S, D, MODE) { \
    float dist_ = (D); \
    float m_ = fminf(fminf(prev, shA), shB); \
    if ((MODE) == 0) m_ = (m_ >= 0.5e30f) ? 0.f : m_; \
    float val_ = fmaf(wd, m_, dist_); \
    float cur_ = val_; \
    if ((MODE) == 0) cur_ = ((S) >= lane) ? val_ : BIGV; \
    if ((MODE) == 3) cur_ = ((S) - lane <= 1023) ? val_ : BIGV; \
    if ((MODE) >= 2) { \
      int t_ = (S) - lane; \
      if ((t_ & 1) == 0) { pend = val_; } \
      else if ((u32)(t_ - 961) < 63u) \
        *(float2*)(oprow + (t_ - 961)) = make_float2(pend, val_); \
    } \
    shB = shA; \
    shA = __int_as_float((int)dpp_shr1((u32)bigbits, (u32)__float_as_int(cur_))); \
    prev = cur_; }

  // 16 steps from quads: even lane step i uses stream[i], odd lane stream[i+1].
#define CONS(Q0,Q1,Q2,Q3,Q4,Q5,Q6,Q7,Q8, S0, MODE) { \
    float v0_  = oddl ? Q0.y : Q0.x, v1_  = oddl ? Q1.x : Q0.y; \
    float v2_  = oddl ? Q1.y : Q1.x, v3_  = oddl ? Q2.x : Q1.y; \
    float v4_  = oddl ? Q2.y : Q2.x, v5_  = oddl ? Q3.x : Q2.y; \
    float v6_  = oddl ? Q3.y : Q3.x, v7_  = oddl ? Q4.x : Q3.y; \
    float v8_  = oddl ? Q4.y : Q4.x, v9_  = oddl ? Q5.x : Q4.y; \
    float v10_ = oddl ? Q5.y : Q5.x, v11_ = oddl ? Q6.x : Q5.y; \
    float v12_ = oddl ? Q6.y : Q6.x, v13_ = oddl ? Q7.x : Q6.y; \
    float v14_ = oddl ? Q7.y : Q7.x, v15_ = oddl ? Q8.x : Q7.y; \
    DPS((S0)+0,  v0_,  MODE); DPS((S0)+1,  v1_,  MODE); \
    DPS((S0)+2,  v2_,  MODE); DPS((S0)+3,  v3_,  MODE); \
    DPS((S0)+4,  v4_,  MODE); DPS((S0)+5,  v5_,  MODE); \
    DPS((S0)+6,  v6_,  MODE); DPS((S0)+7,  v7_,  MODE); \
    DPS((S0)+8,  v8_,  MODE); DPS((S0)+9,  v9_,  MODE); \
    DPS((S0)+10, v10_, MODE); DPS((S0)+11, v11_, MODE); \
    DPS((S0)+12, v12_, MODE); DPS((S0)+13, v13_, MODE); \
    DPS((S0)+14, v14_, MODE); DPS((S0)+15, v15_, MODE); }

#define TILE(C0,C1,C2,C3,C4,C5,C6,C7,C8, N0,N1,N2,N3,N4,N5,N6,N7,N8, S0, MODE, DOPROD, T0) { \
    if (DOPROD) { PRODUCE(T0); } \
    LOAD9(N0,N1,N2,N3,N4,N5,N6,N7,N8); \
    CONS(C0,C1,C2,C3,C4,C5,C6,C7,C8, S0, MODE); }

  float2 A0,A1,A2,A3,A4,A5,A6,A7,A8, B0,B1,B2,B3,B4,B5,B6,B7,B8;

  PRODUCE(0); PRODUCE(16); PRODUCE(32);     // tiles 0-2 (slots 0,1,2)
  LOAD9(A0,A1,A2,A3,A4,A5,A6,A7,A8);        // tile 0 quads

  // tiles 0-3: prologue
  TILE(A0,A1,A2,A3,A4,A5,A6,A7,A8, B0,B1,B2,B3,B4,B5,B6,B7,B8, 0,  0, 1, 48);
  TILE(B0,B1,B2,B3,B4,B5,B6,B7,B8, A0,A1,A2,A3,A4,A5,A6,A7,A8, 16, 0, 1, 64);
  TILE(A0,A1,A2,A3,A4,A5,A6,A7,A8, B0,B1,B2,B3,B4,B5,B6,B7,B8, 32, 0, 1, 80);
  TILE(B0,B1,B2,B3,B4,B5,B6,B7,B8, A0,A1,A2,A3,A4,A5,A6,A7,A8, 48, 0, 1, 96);
  // tiles 4-59: main
#pragma unroll 1
  for (int j = 0; j < 28; ++j) {
    int s0 = 64 + 32 * j;
    TILE(A0,A1,A2,A3,A4,A5,A6,A7,A8, B0,B1,B2,B3,B4,B5,B6,B7,B8, s0,      1, 1, 32*j + 112);
    TILE(B0,B1,B2,B3,B4,B5,B6,B7,B8, A0,A1,A2,A3,A4,A5,A6,A7,A8, s0 + 16, 1, 1, 32*j + 128);
  }
  // tiles 60-63: stores, t<=1023 guaranteed
  TILE(A0,A1,A2,A3,A4,A5,A6,A7,A8, B0,B1,B2,B3,B4,B5,B6,B7,B8, 960,  2, 1, 1008);
  TILE(B0,B1,B2,B3,B4,B5,B6,B7,B8, A0,A1,A2,A3,A4,A5,A6,A7,A8, 976,  2, 0, 0);
  TILE(A0,A1,A2,A3,A4,A5,A6,A7,A8, B0,B1,B2,B3,B4,B5,B6,B7,B8, 992,  2, 0, 0);
  TILE(B0,B1,B2,B3,B4,B5,B6,B7,B8, A0,A1,A2,A3,A4,A5,A6,A7,A8, 1008, 2, 0, 0);
  // tiles 64-67: stores + t<=1023 mask (stale quads only feed masked cells)
  TILE(A0,A1,A2,A3,A4,A5,A6,A7,A8, B0,B1,B2,B3,B4,B5,B6,B7,B8, 1024, 3, 0, 0);
  TILE(B0,B1,B2,B3,B4,B5,B6,B7,B8, A0,A1,A2,A3,A4,A5,A6,A7,A8, 1040, 3, 0, 0);
  TILE(A0,A1,A2,A3,A4,A5,A6,A7,A8, B0,B1,B2,B3,B4,B5,B6,B7,B8, 1056, 3, 0, 0);
  CONS(B0,B1,B2,B3,B4,B5,B6,B7,B8, 1072, 3);
}

extern "C" void kernel_launch(void* const* d_in, const int* in_sizes, int n_in,
                              void* d_out, int out_size, void* d_ws, size_t ws_size,
                              hipStream_t stream) {
  const float* x     = (const float*)d_in[0];
  const float* patts = (const float*)d_in[1];
  float* out         = (float*)d_out;
  const float w = (float)exp(log(0.1) / 64.0);
  dim3 grid(256), block(256);
  hipLaunchKernelGGL(dtw_fused, grid, block, 0, stream, x, patts, out, w);
}